// Round 3
// baseline (803.377 us; speedup 1.0000x reference)
//
#include <hip/hip_runtime.h>

// Sudoku GNN: 5x GCNConv (shared graph) + 2-layer MLP head.
// CSR built once per launch, weight-free (dinv factored into producers).
// XCD-sliced preprocessing: node ids split into 8 slices of 20736; blocks
// process only their slice (slice = blockIdx&7 ~ XCD via round-robin
// dispatch) so deg/cursor atomics and csr writes stay in ONE XCD's L2.
// Mapping is a locality heuristic only — correctness never depends on it.

#define NN    165888            // total nodes = 2048*81
#define NBAT  2048
#define EPER  1620
#define NEDGE (NBAT * EPER)     // 3,317,760
#define ETOT  (NEDGE + NN)      // 3,483,648 (with self loops)
#define SLICE 20736             // NN / 8, multiple of 64

// ---------------- preprocessing ----------------

// Degree histogram, slice-filtered (8x edge re-read, L3-resident).
// Also accumulates per-slice edge totals for CSR region bases.
__global__ __launch_bounds__(256) void k_deg(const int* __restrict__ ei,
                                             int* __restrict__ deg,
                                             int* __restrict__ slice_tot) {
  int s   = blockIdx.x & 7;
  int blk = blockIdx.x >> 3;           // 0..255, 8 batches each
  int cnt = 0;
  for (int b = blk * 8; b < blk * 8 + 8; ++b) {
    const int* dstp = ei + (size_t)b * (2 * EPER) + EPER;
    for (int e = threadIdx.x; e < EPER; e += 256) {
      int dst = dstp[e];
      if (dst / SLICE == s) { atomicAdd(&deg[dst], 1); ++cnt; }
    }
  }
  // block-reduce cnt -> one atomic per block
  __shared__ int sred[4];
#pragma unroll
  for (int off = 32; off > 0; off >>= 1) cnt += __shfl_down(cnt, off);
  if ((threadIdx.x & 63) == 0) sred[threadIdx.x >> 6] = cnt;
  __syncthreads();
  if (threadIdx.x == 0)
    atomicAdd(&slice_tot[s], sred[0] + sred[1] + sred[2] + sred[3]);
}

// Exclusive prefix of slice totals (incl. self-loops) -> per-slice CSR bases.
__global__ void k_base(const int* __restrict__ slice_tot,
                       int* __restrict__ slice_counter) {
  if (threadIdx.x == 0) {
    int acc = 0;
    for (int s = 0; s < 8; ++s) {
      slice_counter[s] = acc;
      acc += slice_tot[s] + SLICE;     // + self loops
    }
  }
}

// Per node: claim CSR segment from its slice's region (wave-scan + 1 atomic
// per wave), write dinv, self-loop entry, cursor.
__global__ __launch_bounds__(256) void k_alloc(const int* __restrict__ deg,
                                               int* __restrict__ slice_counter,
                                               int* __restrict__ row_start,
                                               int* __restrict__ row_end,
                                               float* __restrict__ dinv,
                                               int* __restrict__ csr,
                                               int* __restrict__ cursor) {
  int bi = blockIdx.x;                           // 648 blocks
  int vb = (bi & 7) * 81 + (bi >> 3);            // XCD swizzle: vb's slice == bi&7
  int i  = vb * 256 + threadIdx.x;
  int lane = threadIdx.x & 63;
  int d = deg[i] + 1;                            // + self loop
  int x = d;                                     // inclusive wave scan
#pragma unroll
  for (int off = 1; off < 64; off <<= 1) {
    int y = __shfl_up(x, off);
    if (lane >= off) x += y;
  }
  int total = __shfl(x, 63);
  int s = i / SLICE;                             // wave-uniform (64 | SLICE)
  int base;
  if (lane == 63) base = atomicAdd(&slice_counter[s], total);
  base = __shfl(base, 63);
  int rs = base + x - d;
  row_start[i] = rs;
  row_end[i]   = rs + d;
  dinv[i] = rsqrtf((float)d);
  csr[rs] = i;                                   // self loop
  cursor[i] = rs + 1;
}

// Slice-filtered scatter: cursor atomics + csr writes are XCD-local.
__global__ __launch_bounds__(256) void k_scatter(const int* __restrict__ ei,
                                                 int* __restrict__ cursor,
                                                 int* __restrict__ csr) {
  int s   = blockIdx.x & 7;
  int blk = blockIdx.x >> 3;
  for (int b = blk * 8; b < blk * 8 + 8; ++b) {
    const int* srcp = ei + (size_t)b * (2 * EPER);
    const int* dstp = srcp + EPER;
    for (int e = threadIdx.x; e < EPER; e += 256) {
      int dst = dstp[e];
      if (dst / SLICE == s) {
        int src = srcp[e];
        int pos = atomicAdd(&cursor[dst], 1);
        csr[pos] = src;
      }
    }
  }
}

// ---------------- small row-parallel GEMM ----------------

template <int CI, int CO, bool ADDB, bool RELU, bool SCALE>
__global__ __launch_bounds__(256) void k_gemm(const float* __restrict__ in,
                                              const float* __restrict__ W,
                                              const float* __restrict__ bias,
                                              const float* __restrict__ dinv,
                                              float* __restrict__ out) {
  __shared__ float sW[CI * CO];
  __shared__ float sB[CO];
  int t = threadIdx.x;
  for (int k = t; k < CI * CO; k += 256) sW[k] = W[k];
  if (ADDB) { if (t < CO) sB[t] = bias[t]; }
  __syncthreads();
  int bi = blockIdx.x;
  int vb = (bi & 7) * 81 + (bi >> 3);
  int i  = vb * 256 + t;
  if (i >= NN) return;
  float r[CI];
#pragma unroll
  for (int k = 0; k < CI; ++k) r[k] = in[(size_t)i * CI + k];
  float acc[CO];
#pragma unroll
  for (int j = 0; j < CO; ++j) acc[j] = ADDB ? sB[j] : 0.0f;
#pragma unroll
  for (int k = 0; k < CI; ++k) {
    float rv = r[k];
#pragma unroll
    for (int j = 0; j < CO; ++j) acc[j] = fmaf(rv, sW[k * CO + j], acc[j]);
  }
  float sc = SCALE ? dinv[i] : 1.0f;
#pragma unroll
  for (int j = 0; j < CO; ++j) {
    float v = acc[j];
    if (RELU) v = fmaxf(v, 0.0f);
    if (SCALE) v *= sc;
    out[(size_t)i * CO + j] = v;
  }
}

// Fused: h3 = relu(a3@W3+b3);  g4 = dinv ⊙ (h3@W4)   (32 -> 64 -> 32)
__global__ __launch_bounds__(256) void k_gemm34(const float* __restrict__ in,
                                                const float* __restrict__ W3,
                                                const float* __restrict__ b3,
                                                const float* __restrict__ W4,
                                                const float* __restrict__ dinv,
                                                float* __restrict__ out) {
  __shared__ float sW3[32 * 64];
  __shared__ float sW4[64 * 32];
  __shared__ float sB3[64];
  int t = threadIdx.x;
  for (int k = t; k < 2048; k += 256) { sW3[k] = W3[k]; sW4[k] = W4[k]; }
  if (t < 64) sB3[t] = b3[t];
  __syncthreads();
  int bi = blockIdx.x;
  int vb = (bi & 7) * 81 + (bi >> 3);
  int i  = vb * 256 + t;
  if (i >= NN) return;
  float r[32];
#pragma unroll
  for (int k = 0; k < 32; ++k) r[k] = in[(size_t)i * 32 + k];
  float h[64];
#pragma unroll
  for (int j = 0; j < 64; ++j) h[j] = sB3[j];
#pragma unroll
  for (int k = 0; k < 32; ++k) {
    float rv = r[k];
#pragma unroll
    for (int j = 0; j < 64; ++j) h[j] = fmaf(rv, sW3[k * 64 + j], h[j]);
  }
#pragma unroll
  for (int j = 0; j < 64; ++j) h[j] = fmaxf(h[j], 0.0f);
  float acc[32];
#pragma unroll
  for (int j = 0; j < 32; ++j) acc[j] = 0.0f;
#pragma unroll
  for (int k = 0; k < 64; ++k) {
    float hv = h[k];
#pragma unroll
    for (int j = 0; j < 32; ++j) acc[j] = fmaf(hv, sW4[k * 32 + j], acc[j]);
  }
  float sc = dinv[i];
#pragma unroll
  for (int j = 0; j < 32; ++j) out[(size_t)i * 32 + j] = acc[j] * sc;
}

// ---------------- pull-based aggregation (weight-free) ----------------

template <int C, bool BIASRELU, bool OUTSCALE>
__global__ __launch_bounds__(256) void k_agg(const float* __restrict__ g,
                                             const int* __restrict__ row_start,
                                             const int* __restrict__ row_end,
                                             const int* __restrict__ csr,
                                             const float* __restrict__ dinv,
                                             const float* __restrict__ bias,
                                             float* __restrict__ out) {
  constexpr int LG  = C / 4;       // lanes per node
  constexpr int NPB = 256 / LG;    // nodes per block
  constexpr int SPB = SLICE / NPB; // blocks per slice
  constexpr int EPI = 8;           // edges in flight per iteration
  int t  = threadIdx.x;
  int q  = t & (LG - 1);
  int bi = blockIdx.x;
  int vb = (bi & 7) * SPB + (bi >> 3);           // XCD swizzle
  int i  = vb * NPB + t / LG;
  int gl = (t & 63) & ~(LG - 1);   // group base lane within wave
  int rs = row_start[i];
  int re = row_end[i];
  float4 acc = make_float4(0.f, 0.f, 0.f, 0.f);
  const float* gq = g + (size_t)q * 4;
  for (int p = rs; p < re; p += EPI) {
    int myv[EPI / LG];
#pragma unroll
    for (int u = 0; u < EPI / LG; ++u) {
      int idx = p + u * LG + q;
      myv[u] = csr[idx < re ? idx : re - 1];
    }
#pragma unroll
    for (int j = 0; j < EPI; ++j) {
      if (p + j >= re) break;                      // uniform within lane-group
      int s = __shfl(myv[j / LG], gl + (j & (LG - 1)));
      float4 v = *(const float4*)(gq + (size_t)s * C);
      acc.x += v.x; acc.y += v.y; acc.z += v.z; acc.w += v.w;
    }
  }
  float di = dinv[i];
  acc.x *= di; acc.y *= di; acc.z *= di; acc.w *= di;
  if (BIASRELU) {
    float4 bb = *(const float4*)(bias + q * 4);
    acc.x = fmaxf(acc.x + bb.x, 0.f);
    acc.y = fmaxf(acc.y + bb.y, 0.f);
    acc.z = fmaxf(acc.z + bb.z, 0.f);
    acc.w = fmaxf(acc.w + bb.w, 0.f);
  }
  if (OUTSCALE) { acc.x *= di; acc.y *= di; acc.z *= di; acc.w *= di; }
  *(float4*)(out + (size_t)i * C + q * 4) = acc;
}

// ---------------- fused head MLP: relu(h@fW1+fb1)@fW2+fb2 ----------------

__global__ __launch_bounds__(256) void k_mlp(const float* __restrict__ h,
                                             const float* __restrict__ fW1,
                                             const float* __restrict__ fb1,
                                             const float* __restrict__ fW2,
                                             const float* __restrict__ fb2,
                                             float* __restrict__ out) {
  __shared__ float sW1[256], sW2[144], sB1[16], sB2[9];
  int t = threadIdx.x;
  sW1[t] = fW1[t];
  if (t < 144) sW2[t] = fW2[t];
  if (t < 16)  sB1[t] = fb1[t];
  if (t < 9)   sB2[t] = fb2[t];
  __syncthreads();
  int bi = blockIdx.x;
  int vb = (bi & 7) * 81 + (bi >> 3);
  int i  = vb * 256 + t;
  if (i >= NN) return;
  float r[16];
#pragma unroll
  for (int k = 0; k < 16; ++k) r[k] = h[(size_t)i * 16 + k];
  float z[16];
#pragma unroll
  for (int j = 0; j < 16; ++j) z[j] = sB1[j];
#pragma unroll
  for (int k = 0; k < 16; ++k) {
    float rv = r[k];
#pragma unroll
    for (int j = 0; j < 16; ++j) z[j] = fmaf(rv, sW1[k * 16 + j], z[j]);
  }
#pragma unroll
  for (int j = 0; j < 16; ++j) z[j] = fmaxf(z[j], 0.f);
  float o[9];
#pragma unroll
  for (int j = 0; j < 9; ++j) o[j] = sB2[j];
#pragma unroll
  for (int k = 0; k < 16; ++k) {
    float zv = z[k];
#pragma unroll
    for (int j = 0; j < 9; ++j) o[j] = fmaf(zv, sW2[k * 9 + j], o[j]);
  }
#pragma unroll
  for (int j = 0; j < 9; ++j) out[(size_t)i * 9 + j] = o[j];
}

// ---------------- launch ----------------

extern "C" void kernel_launch(void* const* d_in, const int* in_sizes, int n_in,
                              void* d_out, int out_size, void* d_ws, size_t ws_size,
                              hipStream_t stream) {
  const float* x   = (const float*)d_in[0];
  const int*   ei  = (const int*)d_in[1];
  const float* W1  = (const float*)d_in[2];
  const float* b1  = (const float*)d_in[3];
  const float* W2  = (const float*)d_in[4];
  const float* b2  = (const float*)d_in[5];
  const float* W3  = (const float*)d_in[6];
  const float* b3  = (const float*)d_in[7];
  const float* W4  = (const float*)d_in[8];
  const float* b4  = (const float*)d_in[9];
  const float* W5  = (const float*)d_in[10];
  const float* b5  = (const float*)d_in[11];
  const float* fW1 = (const float*)d_in[12];
  const float* fb1 = (const float*)d_in[13];
  const float* fW2 = (const float*)d_in[14];
  const float* fb2 = (const float*)d_in[15];
  float* out = (float*)d_out;

  char* ws = (char*)d_ws;
  size_t off = 0;
  auto alloc = [&](size_t bytes) -> char* {
    char* p = ws + off;
    off += (bytes + 255) & ~(size_t)255;
    return p;
  };
  int*   deg      = (int*)  alloc((size_t)NN * 4);
  int*   stot     = (int*)  alloc(256);            // slice totals  (memset w/ deg)
  int*   scnt     = (int*)  alloc(256);            // slice counters (set by k_base)
  int*   rs_      = (int*)  alloc((size_t)NN * 4);
  int*   re_      = (int*)  alloc((size_t)NN * 4);
  int*   cur      = (int*)  alloc((size_t)NN * 4);
  float* dinv     = (float*)alloc((size_t)NN * 4);
  int*   csr      = (int*)  alloc((size_t)ETOT * 4);
  float* P16a     = (float*)alloc((size_t)NN * 16 * 4);
  float* P16b     = (float*)alloc((size_t)NN * 16 * 4);
  float* P32a     = (float*)alloc((size_t)NN * 32 * 4);
  float* P32b     = (float*)alloc((size_t)NN * 32 * 4);
  // ~81 MB of ws

  hipMemsetAsync(deg, 0, (size_t)NN * 4 + 512, stream);  // deg + stot (+scnt)

  k_deg<<<2048, 256, 0, stream>>>(ei, deg, stot);
  k_base<<<1, 64, 0, stream>>>(stot, scnt);
  k_alloc<<<NN / 256, 256, 0, stream>>>(deg, scnt, rs_, re_, dinv, csr, cur);
  k_scatter<<<2048, 256, 0, stream>>>(ei, cur, csr);

  const int gN = NN / 256;  // 648
  // L1: g0 = dinv⊙(x@W1); g1 = dinv⊙relu(dinv*Σg0 + b1)
  k_gemm<10, 16, false, false, true><<<gN, 256, 0, stream>>>(x, W1, nullptr, dinv, P16a);
  k_agg<16, true, true ><<<NN / 64, 256, 0, stream>>>(P16a, rs_, re_, csr, dinv, b1, P16b);
  // L2: a2 = dinv*Σg1 ; g2 = dinv⊙relu(a2@W2+b2)
  k_agg<16, false, false><<<NN / 64, 256, 0, stream>>>(P16b, rs_, re_, csr, dinv, nullptr, P16a);
  k_gemm<16, 32, true, true, true><<<gN, 256, 0, stream>>>(P16a, W2, b2, dinv, P32a);
  // L3+L4 front: a3 = dinv*Σg2 ; h3 = relu(a3@W3+b3); g4 = dinv⊙(h3@W4)
  k_agg<32, false, false><<<NN / 32, 256, 0, stream>>>(P32a, rs_, re_, csr, dinv, nullptr, P32b);
  k_gemm34<<<gN, 256, 0, stream>>>(P32b, W3, b3, W4, dinv, P32a);
  // L4 agg: h4 = relu(dinv*Σg4 + b4)
  k_agg<32, true, false><<<NN / 32, 256, 0, stream>>>(P32a, rs_, re_, csr, dinv, b4, P32b);
  // L5: g5 = dinv⊙(h4@W5); h5 = relu(dinv*Σg5 + b5)
  k_gemm<32, 16, false, false, true><<<gN, 256, 0, stream>>>(P32b, W5, nullptr, dinv, P16a);
  k_agg<16, true, false><<<NN / 64, 256, 0, stream>>>(P16a, rs_, re_, csr, dinv, b5, P16b);
  // Head MLP
  k_mlp<<<gN, 256, 0, stream>>>(P16b, fW1, fb1, fW2, fb2, out);
}

// Round 4
// 570.501 us; speedup vs baseline: 1.4082x; 1.4082x over previous
//
#include <hip/hip_runtime.h>

// Sudoku GNN: 5x GCNConv (shared graph) + 2-layer MLP head.
// CSR built once per launch via two-level bucket sort (bucket = dst>>8):
// zero global atomics, zero memsets; all scatters either coalesced or
// confined to one block's ~22KB csr span (lines fill in L2 before writeback).
// Weight-free CSR: norm_ij = dinv_i*dinv_j factors into producers/consumers.

#define NN    165888            // total nodes = 2048*81
#define NBAT  2048
#define EPER  1620
#define NEDGE (NBAT * EPER)     // 3,317,760
#define ETOT  (NEDGE + NN)      // 3,483,648 (with self loops)
#define NBKT  648               // buckets of 256 nodes (dst>>8)
#define NBLK  512               // edge-pass blocks, 4 batches each
#define SLICE 20736             // NN/8 (XCD swizzle for node-parallel kernels)

// ---------------- block-wide exclusive scan (256 threads) ----------------

__device__ inline void blk_scan256(int val, int& excl, int& total, int* sw) {
  int lane = threadIdx.x & 63, w = threadIdx.x >> 6;
  int x = val;
#pragma unroll
  for (int off = 1; off < 64; off <<= 1) {
    int y = __shfl_up(x, off);
    if (lane >= off) x += y;
  }
  if (lane == 63) sw[w] = x;
  __syncthreads();
  int woff = 0;
  if (w > 0) woff = sw[0];
  if (w > 1) woff += sw[1];
  if (w > 2) woff += sw[2];
  total = sw[0] + sw[1] + sw[2] + sw[3];
  excl = woff + x - val;
}

// ---------------- preprocessing ----------------

// Pass 1: per-block bucket histogram (LDS atomics only), coalesced store.
__global__ __launch_bounds__(256) void k_count(const int* __restrict__ ei,
                                               int* __restrict__ counts) {
  __shared__ int cnt[NBKT];
  int t = threadIdx.x;
  for (int k = t; k < NBKT; k += 256) cnt[k] = 0;
  __syncthreads();
  int b0 = blockIdx.x * 4;
  for (int b = b0; b < b0 + 4; ++b) {
    const int* dstp = ei + (size_t)b * (2 * EPER) + EPER;
    for (int e = t; e < EPER; e += 256) atomicAdd(&cnt[dstp[e] >> 8], 1);
  }
  __syncthreads();
  for (int k = t; k < NBKT; k += 256) counts[blockIdx.x * NBKT + k] = cnt[k];
}

// Pass 2: per-bucket exclusive scan over the 512 block counts.
__global__ __launch_bounds__(256) void k_scan(const int* __restrict__ counts,
                                              int* __restrict__ basesT,
                                              int* __restrict__ btot) {
  int bkt = blockIdx.x, t = threadIdx.x;
  int a = counts[(2 * t)     * NBKT + bkt];
  int b = counts[(2 * t + 1) * NBKT + bkt];
  __shared__ int sw[4];
  int excl, tot;
  blk_scan256(a + b, excl, tot, sw);
  basesT[bkt * NBLK + 2 * t]     = excl;
  basesT[bkt * NBLK + 2 * t + 1] = excl + a;
  if (t == 255) btot[bkt] = tot;
}

// Pass 2b: scan bucket totals -> pbase[649].
__global__ __launch_bounds__(1024) void k_pscan(const int* __restrict__ btot,
                                                int* __restrict__ pbase) {
  __shared__ int s[NBKT];
  int t = threadIdx.x;
  if (t < NBKT) s[t] = btot[t];
  __syncthreads();
  for (int off = 1; off < NBKT; off <<= 1) {
    int v = (t < NBKT && t >= off) ? s[t - off] : 0;
    __syncthreads();
    if (t < NBKT) s[t] += v;
    __syncthreads();
  }
  if (t < NBKT) pbase[t + 1] = s[t];
  if (t == 0)   pbase[0] = 0;
}

// Pass 3: scatter packed (src | dstLocal<<24) to bucket-grouped positions.
// Per-(block,bucket) runs are contiguous -> mostly-full-line writes.
__global__ __launch_bounds__(256) void k_scat(const int* __restrict__ ei,
                                              const int* __restrict__ basesT,
                                              const int* __restrict__ pbase,
                                              unsigned int* __restrict__ pairs) {
  __shared__ int cur[NBKT];
  int t = threadIdx.x;
  for (int k = t; k < NBKT; k += 256)
    cur[k] = pbase[k] + basesT[k * NBLK + blockIdx.x];
  __syncthreads();
  int b0 = blockIdx.x * 4;
  for (int b = b0; b < b0 + 4; ++b) {
    const int* srcp = ei + (size_t)b * (2 * EPER);
    const int* dstp = srcp + EPER;
    for (int e = t; e < EPER; e += 256) {
      int d = dstp[e];
      unsigned int s = (unsigned int)srcp[e];
      int pos = atomicAdd(&cur[d >> 8], 1);
      pairs[pos] = s | ((unsigned int)(d & 255) << 24);
    }
  }
}

// Pass 4: one block per bucket. Local histogram+scan -> row bounds, dinv,
// self loops; then scatter src into this bucket's ~22KB csr span.
__global__ __launch_bounds__(256) void k_build(const unsigned int* __restrict__ pairs,
                                               const int* __restrict__ pbase,
                                               int* __restrict__ row_start,
                                               int* __restrict__ row_end,
                                               float* __restrict__ dinv,
                                               int* __restrict__ csr) {
  __shared__ int cnt[256];
  __shared__ int sw[4];
  int bkt = blockIdx.x, t = threadIdx.x;
  cnt[t] = 0;
  __syncthreads();
  int p0 = pbase[bkt], p1 = pbase[bkt + 1];
  for (int k = p0 + t; k < p1; k += 256)
    atomicAdd(&cnt[pairs[k] >> 24], 1);
  __syncthreads();
  int indeg = cnt[t];
  int excl, tot;
  blk_scan256(indeg, excl, tot, sw);
  int csrbase = p0 + bkt * 256;                 // + self-loop slots of prior buckets
  int rs   = csrbase + excl + t;                // + own prior self loops
  int node = bkt * 256 + t;
  int d    = indeg + 1;
  row_start[node] = rs;
  row_end[node]   = rs + d;
  dinv[node] = rsqrtf((float)d);
  csr[rs] = node;                               // self loop
  __syncthreads();
  cnt[t] = rs + 1;                              // reuse as cursors
  __syncthreads();
  for (int k = p0 + t; k < p1; k += 256) {
    unsigned int pr = pairs[k];
    int pos = atomicAdd(&cnt[pr >> 24], 1);
    csr[pos] = (int)(pr & 0x00FFFFFFu);
  }
}

// ---------------- small row-parallel GEMM ----------------

template <int CI, int CO, bool ADDB, bool RELU, bool SCALE>
__global__ __launch_bounds__(256) void k_gemm(const float* __restrict__ in,
                                              const float* __restrict__ W,
                                              const float* __restrict__ bias,
                                              const float* __restrict__ dinv,
                                              float* __restrict__ out) {
  __shared__ float sW[CI * CO];
  __shared__ float sB[CO];
  int t = threadIdx.x;
  for (int k = t; k < CI * CO; k += 256) sW[k] = W[k];
  if (ADDB) { if (t < CO) sB[t] = bias[t]; }
  __syncthreads();
  int bi = blockIdx.x;
  int vb = (bi & 7) * 81 + (bi >> 3);
  int i  = vb * 256 + t;
  float r[CI];
#pragma unroll
  for (int k = 0; k < CI; ++k) r[k] = in[(size_t)i * CI + k];
  float acc[CO];
#pragma unroll
  for (int j = 0; j < CO; ++j) acc[j] = ADDB ? sB[j] : 0.0f;
#pragma unroll
  for (int k = 0; k < CI; ++k) {
    float rv = r[k];
#pragma unroll
    for (int j = 0; j < CO; ++j) acc[j] = fmaf(rv, sW[k * CO + j], acc[j]);
  }
  float sc = SCALE ? dinv[i] : 1.0f;
#pragma unroll
  for (int j = 0; j < CO; ++j) {
    float v = acc[j];
    if (RELU) v = fmaxf(v, 0.0f);
    if (SCALE) v *= sc;
    out[(size_t)i * CO + j] = v;
  }
}

// Fused: h3 = relu(a3@W3+b3);  g4 = dinv ⊙ (h3@W4)   (32 -> 64 -> 32)
__global__ __launch_bounds__(256) void k_gemm34(const float* __restrict__ in,
                                                const float* __restrict__ W3,
                                                const float* __restrict__ b3,
                                                const float* __restrict__ W4,
                                                const float* __restrict__ dinv,
                                                float* __restrict__ out) {
  __shared__ float sW3[32 * 64];
  __shared__ float sW4[64 * 32];
  __shared__ float sB3[64];
  int t = threadIdx.x;
  for (int k = t; k < 2048; k += 256) { sW3[k] = W3[k]; sW4[k] = W4[k]; }
  if (t < 64) sB3[t] = b3[t];
  __syncthreads();
  int bi = blockIdx.x;
  int vb = (bi & 7) * 81 + (bi >> 3);
  int i  = vb * 256 + t;
  float r[32];
#pragma unroll
  for (int k = 0; k < 32; ++k) r[k] = in[(size_t)i * 32 + k];
  float h[64];
#pragma unroll
  for (int j = 0; j < 64; ++j) h[j] = sB3[j];
#pragma unroll
  for (int k = 0; k < 32; ++k) {
    float rv = r[k];
#pragma unroll
    for (int j = 0; j < 64; ++j) h[j] = fmaf(rv, sW3[k * 64 + j], h[j]);
  }
#pragma unroll
  for (int j = 0; j < 64; ++j) h[j] = fmaxf(h[j], 0.0f);
  float acc[32];
#pragma unroll
  for (int j = 0; j < 32; ++j) acc[j] = 0.0f;
#pragma unroll
  for (int k = 0; k < 64; ++k) {
    float hv = h[k];
#pragma unroll
    for (int j = 0; j < 32; ++j) acc[j] = fmaf(hv, sW4[k * 32 + j], acc[j]);
  }
  float sc = dinv[i];
#pragma unroll
  for (int j = 0; j < 32; ++j) out[(size_t)i * 32 + j] = acc[j] * sc;
}

// ---------------- pull-based aggregation (weight-free) ----------------

template <int C, bool BIASRELU, bool OUTSCALE>
__global__ __launch_bounds__(256) void k_agg(const float* __restrict__ g,
                                             const int* __restrict__ row_start,
                                             const int* __restrict__ row_end,
                                             const int* __restrict__ csr,
                                             const float* __restrict__ dinv,
                                             const float* __restrict__ bias,
                                             float* __restrict__ out) {
  constexpr int LG  = C / 4;       // lanes per node
  constexpr int NPB = 256 / LG;    // nodes per block
  constexpr int SPB = SLICE / NPB; // blocks per slice
  constexpr int EPI = 8;           // edges in flight per iteration
  int t  = threadIdx.x;
  int q  = t & (LG - 1);
  int bi = blockIdx.x;
  int vb = (bi & 7) * SPB + (bi >> 3);           // XCD swizzle
  int i  = vb * NPB + t / LG;
  int gl = (t & 63) & ~(LG - 1);   // group base lane within wave
  int rs = row_start[i];
  int re = row_end[i];
  float4 acc = make_float4(0.f, 0.f, 0.f, 0.f);
  const float* gq = g + (size_t)q * 4;
  for (int p = rs; p < re; p += EPI) {
    int myv[EPI / LG];
#pragma unroll
    for (int u = 0; u < EPI / LG; ++u) {
      int idx = p + u * LG + q;
      myv[u] = csr[idx < re ? idx : re - 1];
    }
#pragma unroll
    for (int j = 0; j < EPI; ++j) {
      if (p + j >= re) break;                      // uniform within lane-group
      int s = __shfl(myv[j / LG], gl + (j & (LG - 1)));
      float4 v = *(const float4*)(gq + (size_t)s * C);
      acc.x += v.x; acc.y += v.y; acc.z += v.z; acc.w += v.w;
    }
  }
  float di = dinv[i];
  acc.x *= di; acc.y *= di; acc.z *= di; acc.w *= di;
  if (BIASRELU) {
    float4 bb = *(const float4*)(bias + q * 4);
    acc.x = fmaxf(acc.x + bb.x, 0.f);
    acc.y = fmaxf(acc.y + bb.y, 0.f);
    acc.z = fmaxf(acc.z + bb.z, 0.f);
    acc.w = fmaxf(acc.w + bb.w, 0.f);
  }
  if (OUTSCALE) { acc.x *= di; acc.y *= di; acc.z *= di; acc.w *= di; }
  *(float4*)(out + (size_t)i * C + q * 4) = acc;
}

// ---------------- fused head MLP: relu(h@fW1+fb1)@fW2+fb2 ----------------

__global__ __launch_bounds__(256) void k_mlp(const float* __restrict__ h,
                                             const float* __restrict__ fW1,
                                             const float* __restrict__ fb1,
                                             const float* __restrict__ fW2,
                                             const float* __restrict__ fb2,
                                             float* __restrict__ out) {
  __shared__ float sW1[256], sW2[144], sB1[16], sB2[9];
  int t = threadIdx.x;
  sW1[t] = fW1[t];
  if (t < 144) sW2[t] = fW2[t];
  if (t < 16)  sB1[t] = fb1[t];
  if (t < 9)   sB2[t] = fb2[t];
  __syncthreads();
  int bi = blockIdx.x;
  int vb = (bi & 7) * 81 + (bi >> 3);
  int i  = vb * 256 + t;
  float r[16];
#pragma unroll
  for (int k = 0; k < 16; ++k) r[k] = h[(size_t)i * 16 + k];
  float z[16];
#pragma unroll
  for (int j = 0; j < 16; ++j) z[j] = sB1[j];
#pragma unroll
  for (int k = 0; k < 16; ++k) {
    float rv = r[k];
#pragma unroll
    for (int j = 0; j < 16; ++j) z[j] = fmaf(rv, sW1[k * 16 + j], z[j]);
  }
#pragma unroll
  for (int j = 0; j < 16; ++j) z[j] = fmaxf(z[j], 0.f);
  float o[9];
#pragma unroll
  for (int j = 0; j < 9; ++j) o[j] = sB2[j];
#pragma unroll
  for (int k = 0; k < 16; ++k) {
    float zv = z[k];
#pragma unroll
    for (int j = 0; j < 9; ++j) o[j] = fmaf(zv, sW2[k * 9 + j], o[j]);
  }
#pragma unroll
  for (int j = 0; j < 9; ++j) out[(size_t)i * 9 + j] = o[j];
}

// ---------------- launch ----------------

extern "C" void kernel_launch(void* const* d_in, const int* in_sizes, int n_in,
                              void* d_out, int out_size, void* d_ws, size_t ws_size,
                              hipStream_t stream) {
  const float* x   = (const float*)d_in[0];
  const int*   ei  = (const int*)d_in[1];
  const float* W1  = (const float*)d_in[2];
  const float* b1  = (const float*)d_in[3];
  const float* W2  = (const float*)d_in[4];
  const float* b2  = (const float*)d_in[5];
  const float* W3  = (const float*)d_in[6];
  const float* b3  = (const float*)d_in[7];
  const float* W4  = (const float*)d_in[8];
  const float* b4  = (const float*)d_in[9];
  const float* W5  = (const float*)d_in[10];
  const float* b5  = (const float*)d_in[11];
  const float* fW1 = (const float*)d_in[12];
  const float* fb1 = (const float*)d_in[13];
  const float* fW2 = (const float*)d_in[14];
  const float* fb2 = (const float*)d_in[15];
  float* out = (float*)d_out;

  char* ws = (char*)d_ws;
  size_t off = 0;
  auto alloc = [&](size_t bytes) -> char* {
    char* p = ws + off;
    off += (bytes + 255) & ~(size_t)255;
    return p;
  };
  int*   counts  = (int*)  alloc((size_t)NBLK * NBKT * 4);   // 1.33 MB
  int*   basesT  = (int*)  alloc((size_t)NBKT * NBLK * 4);   // 1.33 MB
  int*   btot    = (int*)  alloc((size_t)NBKT * 4);
  int*   pbase   = (int*)  alloc((size_t)(NBKT + 1) * 4);
  unsigned int* pairs = (unsigned int*)alloc((size_t)NEDGE * 4);  // 13.3 MB
  int*   rs_     = (int*)  alloc((size_t)NN * 4);
  int*   re_     = (int*)  alloc((size_t)NN * 4);
  float* dinv    = (float*)alloc((size_t)NN * 4);
  int*   csr     = (int*)  alloc((size_t)ETOT * 4);          // 13.9 MB
  float* P16a    = (float*)alloc((size_t)NN * 16 * 4);
  float* P16b    = (float*)alloc((size_t)NN * 16 * 4);
  float* P32a    = (float*)alloc((size_t)NN * 32 * 4);
  float* P32b    = (float*)alloc((size_t)NN * 32 * 4);
  // ~95 MB of ws; every word read is written first (no memsets needed)

  k_count<<<NBLK, 256, 0, stream>>>(ei, counts);
  k_scan <<<NBKT, 256, 0, stream>>>(counts, basesT, btot);
  k_pscan<<<1, 1024, 0, stream>>>(btot, pbase);
  k_scat <<<NBLK, 256, 0, stream>>>(ei, basesT, pbase, pairs);
  k_build<<<NBKT, 256, 0, stream>>>(pairs, pbase, rs_, re_, dinv, csr);

  const int gN = NN / 256;  // 648
  // L1: g0 = dinv⊙(x@W1); g1 = dinv⊙relu(dinv*Σg0 + b1)
  k_gemm<10, 16, false, false, true><<<gN, 256, 0, stream>>>(x, W1, nullptr, dinv, P16a);
  k_agg<16, true, true ><<<NN / 64, 256, 0, stream>>>(P16a, rs_, re_, csr, dinv, b1, P16b);
  // L2: a2 = dinv*Σg1 ; g2 = dinv⊙relu(a2@W2+b2)
  k_agg<16, false, false><<<NN / 64, 256, 0, stream>>>(P16b, rs_, re_, csr, dinv, nullptr, P16a);
  k_gemm<16, 32, true, true, true><<<gN, 256, 0, stream>>>(P16a, W2, b2, dinv, P32a);
  // L3+L4 front: a3 = dinv*Σg2 ; h3 = relu(a3@W3+b3); g4 = dinv⊙(h3@W4)
  k_agg<32, false, false><<<NN / 32, 256, 0, stream>>>(P32a, rs_, re_, csr, dinv, nullptr, P32b);
  k_gemm34<<<gN, 256, 0, stream>>>(P32b, W3, b3, W4, dinv, P32a);
  // L4 agg: h4 = relu(dinv*Σg4 + b4)
  k_agg<32, true, false><<<NN / 32, 256, 0, stream>>>(P32a, rs_, re_, csr, dinv, b4, P32b);
  // L5: g5 = dinv⊙(h4@W5); h5 = relu(dinv*Σg5 + b5)
  k_gemm<32, 16, false, false, true><<<gN, 256, 0, stream>>>(P32b, W5, nullptr, dinv, P16a);
  k_agg<16, true, false><<<NN / 64, 256, 0, stream>>>(P16a, rs_, re_, csr, dinv, b5, P16b);
  // Head MLP
  k_mlp<<<gN, 256, 0, stream>>>(P16b, fW1, fb1, fW2, fb2, out);
}

// Round 5
// 467.539 us; speedup vs baseline: 1.7183x; 1.2202x over previous
//
#include <hip/hip_runtime.h>

// Sudoku GNN: 5x GCNConv (shared graph) + 2-layer MLP head.
// CSR via two-level bucket sort (no global atomics). Weight-free CSR
// (dinv factored into producers/consumers). Aggregations are pull-based,
// branchless 8-deep-ILP gathers, each FUSED with the following dense
// stage (GEMV/MLP) through an LDS row-stage epilogue.

#define NN    165888            // total nodes = 2048*81
#define NBAT  2048
#define EPER  1620
#define NEDGE (NBAT * EPER)     // 3,317,760
#define ETOT  (NEDGE + NN)      // 3,483,648 (with self loops)
#define NBKT  648               // buckets of 256 nodes (dst>>8)
#define NBLK  512               // edge-pass blocks, 4 batches each
#define SLICE 20736             // NN/8 (XCD swizzle for node-parallel kernels)

// ---------------- block-wide exclusive scan (256 threads) ----------------

__device__ inline void blk_scan256(int val, int& excl, int& total, int* sw) {
  int lane = threadIdx.x & 63, w = threadIdx.x >> 6;
  int x = val;
#pragma unroll
  for (int off = 1; off < 64; off <<= 1) {
    int y = __shfl_up(x, off);
    if (lane >= off) x += y;
  }
  if (lane == 63) sw[w] = x;
  __syncthreads();
  int woff = 0;
  if (w > 0) woff = sw[0];
  if (w > 1) woff += sw[1];
  if (w > 2) woff += sw[2];
  total = sw[0] + sw[1] + sw[2] + sw[3];
  excl = woff + x - val;
}

// ---------------- preprocessing ----------------

__global__ __launch_bounds__(256) void k_count(const int* __restrict__ ei,
                                               int* __restrict__ counts) {
  __shared__ int cnt[NBKT];
  int t = threadIdx.x;
  for (int k = t; k < NBKT; k += 256) cnt[k] = 0;
  __syncthreads();
  int b0 = blockIdx.x * 4;
  for (int b = b0; b < b0 + 4; ++b) {
    const int* dstp = ei + (size_t)b * (2 * EPER) + EPER;
    for (int e = t; e < EPER; e += 256) atomicAdd(&cnt[dstp[e] >> 8], 1);
  }
  __syncthreads();
  for (int k = t; k < NBKT; k += 256) counts[blockIdx.x * NBKT + k] = cnt[k];
}

__global__ __launch_bounds__(256) void k_scan(const int* __restrict__ counts,
                                              int* __restrict__ basesT,
                                              int* __restrict__ btot) {
  int bkt = blockIdx.x, t = threadIdx.x;
  int a = counts[(2 * t)     * NBKT + bkt];
  int b = counts[(2 * t + 1) * NBKT + bkt];
  __shared__ int sw[4];
  int excl, tot;
  blk_scan256(a + b, excl, tot, sw);
  basesT[bkt * NBLK + 2 * t]     = excl;
  basesT[bkt * NBLK + 2 * t + 1] = excl + a;
  if (t == 255) btot[bkt] = tot;
}

__global__ __launch_bounds__(1024) void k_pscan(const int* __restrict__ btot,
                                                int* __restrict__ pbase) {
  __shared__ int s[NBKT];
  int t = threadIdx.x;
  if (t < NBKT) s[t] = btot[t];
  __syncthreads();
  for (int off = 1; off < NBKT; off <<= 1) {
    int v = (t < NBKT && t >= off) ? s[t - off] : 0;
    __syncthreads();
    if (t < NBKT) s[t] += v;
    __syncthreads();
  }
  if (t < NBKT) pbase[t + 1] = s[t];
  if (t == 0)   pbase[0] = 0;
}

__global__ __launch_bounds__(256) void k_scat(const int* __restrict__ ei,
                                              const int* __restrict__ basesT,
                                              const int* __restrict__ pbase,
                                              unsigned int* __restrict__ pairs) {
  __shared__ int cur[NBKT];
  int t = threadIdx.x;
  for (int k = t; k < NBKT; k += 256)
    cur[k] = pbase[k] + basesT[k * NBLK + blockIdx.x];
  __syncthreads();
  int b0 = blockIdx.x * 4;
  for (int b = b0; b < b0 + 4; ++b) {
    const int* srcp = ei + (size_t)b * (2 * EPER);
    const int* dstp = srcp + EPER;
    for (int e = t; e < EPER; e += 256) {
      int d = dstp[e];
      unsigned int s = (unsigned int)srcp[e];
      int pos = atomicAdd(&cur[d >> 8], 1);
      pairs[pos] = s | ((unsigned int)(d & 255) << 24);
    }
  }
}

__global__ __launch_bounds__(256) void k_build(const unsigned int* __restrict__ pairs,
                                               const int* __restrict__ pbase,
                                               int* __restrict__ row_start,
                                               int* __restrict__ row_end,
                                               float* __restrict__ dinv,
                                               int* __restrict__ csr) {
  __shared__ int cnt[256];
  __shared__ int sw[4];
  int bkt = blockIdx.x, t = threadIdx.x;
  cnt[t] = 0;
  __syncthreads();
  int p0 = pbase[bkt], p1 = pbase[bkt + 1];
  for (int k = p0 + t; k < p1; k += 256)
    atomicAdd(&cnt[pairs[k] >> 24], 1);
  __syncthreads();
  int indeg = cnt[t];
  int excl, tot;
  blk_scan256(indeg, excl, tot, sw);
  int csrbase = p0 + bkt * 256;
  int rs   = csrbase + excl + t;
  int node = bkt * 256 + t;
  int d    = indeg + 1;
  row_start[node] = rs;
  row_end[node]   = rs + d;
  dinv[node] = rsqrtf((float)d);
  csr[rs] = node;                               // self loop
  __syncthreads();
  cnt[t] = rs + 1;                              // reuse as cursors
  __syncthreads();
  for (int k = p0 + t; k < p1; k += 256) {
    unsigned int pr = pairs[k];
    int pos = atomicAdd(&cnt[pr >> 24], 1);
    csr[pos] = (int)(pr & 0x00FFFFFFu);
  }
}

// ---------------- branchless agg core: 8 gathers in flight ----------------
// q = lane in group (0..C/4-1), gl = group base lane in wave. rs/re are
// group-uniform. Clamped CSR index + cndmask weight -> no divergent break.

template <int C>
__device__ inline float4 agg_core(const float* __restrict__ g,
                                  const int* __restrict__ csr,
                                  int rs, int re, int q, int gl) {
  constexpr int LG  = C / 4;
  constexpr int EPI = 8;
  float4 acc = make_float4(0.f, 0.f, 0.f, 0.f);
  const float* gq = g + (size_t)q * 4;
  for (int p = rs; p < re; p += EPI) {
    int m[EPI / LG];
#pragma unroll
    for (int u = 0; u < EPI / LG; ++u) {
      int idx = p + u * LG + q;
      m[u] = csr[idx < re ? idx : re - 1];
    }
    float4 v[EPI];
#pragma unroll
    for (int j = 0; j < EPI; ++j) {
      int s = __shfl(m[j / LG], gl + (j % LG));
      v[j] = *(const float4*)(gq + (size_t)s * C);
    }
#pragma unroll
    for (int j = 0; j < EPI; ++j) {
      float w = (p + j < re) ? 1.0f : 0.0f;
      acc.x = fmaf(w, v[j].x, acc.x);
      acc.y = fmaf(w, v[j].y, acc.y);
      acc.z = fmaf(w, v[j].z, acc.z);
      acc.w = fmaf(w, v[j].w, acc.w);
    }
  }
  return acc;
}

// ---------------- K1: g0 = dinv ⊙ (x @ W1)  (10 -> 16) ----------------

__global__ __launch_bounds__(256) void k_gemm1(const float* __restrict__ in,
                                               const float* __restrict__ W,
                                               const float* __restrict__ dinv,
                                               float* __restrict__ out) {
  __shared__ float sW[10 * 16];
  int t = threadIdx.x;
  if (t < 160) sW[t] = W[t];
  __syncthreads();
  int bi = blockIdx.x;
  int vb = (bi & 7) * 81 + (bi >> 3);
  int i  = vb * 256 + t;
  float r[10];
#pragma unroll
  for (int k = 0; k < 10; ++k) r[k] = in[(size_t)i * 10 + k];
  float acc[16];
#pragma unroll
  for (int j = 0; j < 16; ++j) acc[j] = 0.0f;
#pragma unroll
  for (int k = 0; k < 10; ++k) {
    float rv = r[k];
#pragma unroll
    for (int j = 0; j < 16; ++j) acc[j] = fmaf(rv, sW[k * 16 + j], acc[j]);
  }
  float sc = dinv[i];
#pragma unroll
  for (int j = 0; j < 16; ++j) out[(size_t)i * 16 + j] = acc[j] * sc;
}

// ---------------- K2: g1 = dinv ⊙ relu(dinv·Σg0 + b1)  (C=16) ----------------

__global__ __launch_bounds__(256) void k_agg_ep16(const float* __restrict__ g,
                                                  const int* __restrict__ row_start,
                                                  const int* __restrict__ row_end,
                                                  const int* __restrict__ csr,
                                                  const float* __restrict__ dinv,
                                                  const float* __restrict__ bias,
                                                  float* __restrict__ out) {
  constexpr int LG = 4, NPB = 64, SPB = SLICE / NPB;
  int t  = threadIdx.x;
  int q  = t & (LG - 1);
  int bi = blockIdx.x;
  int vb = (bi & 7) * SPB + (bi >> 3);
  int i  = vb * NPB + t / LG;
  int gl = (t & 63) & ~(LG - 1);
  float4 acc = agg_core<16>(g, csr, row_start[i], row_end[i], q, gl);
  float di = dinv[i];
  float4 bb = *(const float4*)(bias + q * 4);
  acc.x = fmaxf(fmaf(di, acc.x, bb.x), 0.f) * di;
  acc.y = fmaxf(fmaf(di, acc.y, bb.y), 0.f) * di;
  acc.z = fmaxf(fmaf(di, acc.z, bb.z), 0.f) * di;
  acc.w = fmaxf(fmaf(di, acc.w, bb.w), 0.f) * di;
  *(float4*)(out + (size_t)i * 16 + q * 4) = acc;
}

// ---------------- K3: a2 = dinv·Σg1 ; g2 = dinv ⊙ relu(a2@W2+b2) (16->32) ----

__global__ __launch_bounds__(256) void k_agg_g2(const float* __restrict__ g,
                                                const int* __restrict__ row_start,
                                                const int* __restrict__ row_end,
                                                const int* __restrict__ csr,
                                                const float* __restrict__ dinv,
                                                const float* __restrict__ W2,
                                                const float* __restrict__ b2,
                                                float* __restrict__ out) {
  constexpr int CI = 16, CO = 32, LG = 4, NPB = 64, SPB = SLICE / NPB, RP = 20;
  __shared__ float sW[CI * CO];
  __shared__ float sB[CO];
  __shared__ float rows[NPB * RP];
  __shared__ float sdi[NPB];
  int t = threadIdx.x;
  for (int k = t; k < CI * CO; k += 256) sW[k] = W2[k];
  if (t < CO) sB[t] = b2[t];
  int bi = blockIdx.x;
  int vb = (bi & 7) * SPB + (bi >> 3);
  int nbase = vb * NPB;
  int q = t & (LG - 1), nl = t / LG;
  int i = nbase + nl;
  int gl = (t & 63) & ~(LG - 1);
  float4 acc = agg_core<16>(g, csr, row_start[i], row_end[i], q, gl);
  float di = dinv[i];
  acc.x *= di; acc.y *= di; acc.z *= di; acc.w *= di;
  *(float4*)&rows[nl * RP + q * 4] = acc;
  if (q == 0) sdi[nl] = di;
  __syncthreads();
  int n2 = t >> 2, c = t & 3;                  // 4 threads/node, 8 outs each
  float o[8];
#pragma unroll
  for (int j = 0; j < 8; ++j) o[j] = sB[c * 8 + j];
  const float* row = &rows[n2 * RP];
#pragma unroll
  for (int k = 0; k < CI; ++k) {
    float rv = row[k];
#pragma unroll
    for (int j = 0; j < 8; ++j) o[j] = fmaf(rv, sW[k * CO + c * 8 + j], o[j]);
  }
  float d2 = sdi[n2];
#pragma unroll
  for (int j = 0; j < 8; ++j) o[j] = fmaxf(o[j], 0.f) * d2;
  float* op = out + (size_t)(nbase + n2) * CO + c * 8;
  *(float4*)op       = make_float4(o[0], o[1], o[2], o[3]);
  *(float4*)(op + 4) = make_float4(o[4], o[5], o[6], o[7]);
}

// ---- K4: a3 = dinv·Σg2 ; h3 = relu(a3@W3+b3); g4 = dinv⊙(h3@W4) (32->64->32) --

__global__ __launch_bounds__(256) void k_agg_g34(const float* __restrict__ g,
                                                 const int* __restrict__ row_start,
                                                 const int* __restrict__ row_end,
                                                 const int* __restrict__ csr,
                                                 const float* __restrict__ dinv,
                                                 const float* __restrict__ W3,
                                                 const float* __restrict__ b3,
                                                 const float* __restrict__ W4,
                                                 float* __restrict__ out) {
  constexpr int LG = 8, NPB = 32, SPB = SLICE / NPB, RP = 36, HP = 68;
  __shared__ float sW3[32 * 64];
  __shared__ float sW4[64 * 32];
  __shared__ float sB3[64];
  __shared__ float rows[NPB * RP];
  __shared__ float hrows[NPB * HP];
  __shared__ float sdi[NPB];
  int t = threadIdx.x;
  for (int k = t; k < 2048; k += 256) { sW3[k] = W3[k]; sW4[k] = W4[k]; }
  if (t < 64) sB3[t] = b3[t];
  int bi = blockIdx.x;
  int vb = (bi & 7) * SPB + (bi >> 3);
  int nbase = vb * NPB;
  int q = t & (LG - 1), nl = t / LG;
  int i = nbase + nl;
  int gl = (t & 63) & ~(LG - 1);
  float4 acc = agg_core<32>(g, csr, row_start[i], row_end[i], q, gl);
  float di = dinv[i];
  acc.x *= di; acc.y *= di; acc.z *= di; acc.w *= di;
  *(float4*)&rows[nl * RP + q * 4] = acc;
  if (q == 0) sdi[nl] = di;
  __syncthreads();
  int n2 = t >> 3, c = t & 7;                  // 8 threads/node
  {                                            // stage 1: 8 of 64 h each
    float o[8];
#pragma unroll
    for (int j = 0; j < 8; ++j) o[j] = sB3[c * 8 + j];
    const float* row = &rows[n2 * RP];
#pragma unroll
    for (int k = 0; k < 32; ++k) {
      float rv = row[k];
#pragma unroll
      for (int j = 0; j < 8; ++j) o[j] = fmaf(rv, sW3[k * 64 + c * 8 + j], o[j]);
    }
    float* hp = &hrows[n2 * HP + c * 8];
#pragma unroll
    for (int j = 0; j < 8; ++j) hp[j] = fmaxf(o[j], 0.f);
  }
  __syncthreads();
  {                                            // stage 2: 4 of 32 outs each
    float o[4] = {0.f, 0.f, 0.f, 0.f};
    const float* hp = &hrows[n2 * HP];
#pragma unroll
    for (int k = 0; k < 64; ++k) {
      float hv = hp[k];
#pragma unroll
      for (int j = 0; j < 4; ++j) o[j] = fmaf(hv, sW4[k * 32 + c * 4 + j], o[j]);
    }
    float d2 = sdi[n2];
#pragma unroll
    for (int j = 0; j < 4; ++j) o[j] *= d2;
    *(float4*)(out + (size_t)(nbase + n2) * 32 + c * 4)
        = make_float4(o[0], o[1], o[2], o[3]);
  }
}

// ---- K5: h4 = relu(dinv·Σg4 + b4); g5 = dinv⊙(h4@W5)  (32->16) ----------

__global__ __launch_bounds__(256) void k_agg_g5(const float* __restrict__ g,
                                                const int* __restrict__ row_start,
                                                const int* __restrict__ row_end,
                                                const int* __restrict__ csr,
                                                const float* __restrict__ dinv,
                                                const float* __restrict__ b4,
                                                const float* __restrict__ W5,
                                                float* __restrict__ out) {
  constexpr int LG = 8, NPB = 32, SPB = SLICE / NPB, RP = 36;
  __shared__ float sW[32 * 16];
  __shared__ float rows[NPB * RP];
  __shared__ float sdi[NPB];
  int t = threadIdx.x;
  for (int k = t; k < 512; k += 256) sW[k] = W5[k];
  int bi = blockIdx.x;
  int vb = (bi & 7) * SPB + (bi >> 3);
  int nbase = vb * NPB;
  int q = t & (LG - 1), nl = t / LG;
  int i = nbase + nl;
  int gl = (t & 63) & ~(LG - 1);
  float4 acc = agg_core<32>(g, csr, row_start[i], row_end[i], q, gl);
  float di = dinv[i];
  float4 bb = *(const float4*)(b4 + q * 4);
  acc.x = fmaxf(fmaf(di, acc.x, bb.x), 0.f);
  acc.y = fmaxf(fmaf(di, acc.y, bb.y), 0.f);
  acc.z = fmaxf(fmaf(di, acc.z, bb.z), 0.f);
  acc.w = fmaxf(fmaf(di, acc.w, bb.w), 0.f);
  *(float4*)&rows[nl * RP + q * 4] = acc;
  if (q == 0) sdi[nl] = di;
  __syncthreads();
  int n2 = t >> 3, c = t & 7;                  // 8 threads/node, 2 outs each
  float o0 = 0.f, o1 = 0.f;
  const float* row = &rows[n2 * RP];
#pragma unroll
  for (int k = 0; k < 32; ++k) {
    float rv = row[k];
    o0 = fmaf(rv, sW[k * 16 + c * 2],     o0);
    o1 = fmaf(rv, sW[k * 16 + c * 2 + 1], o1);
  }
  float d2 = sdi[n2];
  *(float2*)(out + (size_t)(nbase + n2) * 16 + c * 2) = make_float2(o0 * d2, o1 * d2);
}

// ---- K6: h5 = relu(dinv·Σg5 + b5); out = relu(h5@fW1+fb1)@fW2+fb2 --------

__global__ __launch_bounds__(256) void k_agg_mlp(const float* __restrict__ g,
                                                 const int* __restrict__ row_start,
                                                 const int* __restrict__ row_end,
                                                 const int* __restrict__ csr,
                                                 const float* __restrict__ dinv,
                                                 const float* __restrict__ b5,
                                                 const float* __restrict__ fW1,
                                                 const float* __restrict__ fb1,
                                                 const float* __restrict__ fW2,
                                                 const float* __restrict__ fb2,
                                                 float* __restrict__ out) {
  constexpr int LG = 4, NPB = 64, SPB = SLICE / NPB, RP = 20;
  __shared__ float sW1[256], sW2[144], sB1[16], sB2[9];
  __shared__ float rows[NPB * RP];
  __shared__ float zrows[NPB * RP];
  __shared__ float ost[NPB * 9];
  int t = threadIdx.x;
  sW1[t] = fW1[t];
  if (t < 144) sW2[t] = fW2[t];
  if (t < 16)  sB1[t] = fb1[t];
  if (t < 9)   sB2[t] = fb2[t];
  int bi = blockIdx.x;
  int vb = (bi & 7) * SPB + (bi >> 3);
  int nbase = vb * NPB;
  int q = t & (LG - 1), nl = t / LG;
  int i = nbase + nl;
  int gl = (t & 63) & ~(LG - 1);
  float4 acc = agg_core<16>(g, csr, row_start[i], row_end[i], q, gl);
  float di = dinv[i];
  float4 bb = *(const float4*)(b5 + q * 4);
  acc.x = fmaxf(fmaf(di, acc.x, bb.x), 0.f);
  acc.y = fmaxf(fmaf(di, acc.y, bb.y), 0.f);
  acc.z = fmaxf(fmaf(di, acc.z, bb.z), 0.f);
  acc.w = fmaxf(fmaf(di, acc.w, bb.w), 0.f);
  *(float4*)&rows[nl * RP + q * 4] = acc;
  __syncthreads();
  int n2 = t >> 2, c = t & 3;                  // 4 threads/node
  {                                            // z = relu(h5@fW1+fb1), 4 each
    float o[4];
#pragma unroll
    for (int j = 0; j < 4; ++j) o[j] = sB1[c * 4 + j];
    const float* row = &rows[n2 * RP];
#pragma unroll
    for (int k = 0; k < 16; ++k) {
      float rv = row[k];
#pragma unroll
      for (int j = 0; j < 4; ++j) o[j] = fmaf(rv, sW1[k * 16 + c * 4 + j], o[j]);
    }
    float* zp = &zrows[n2 * RP + c * 4];
#pragma unroll
    for (int j = 0; j < 4; ++j) zp[j] = fmaxf(o[j], 0.f);
  }
  __syncthreads();
  if (c < 3) {                                 // 3 outs each (3x3 = 9)
    float o[3];
#pragma unroll
    for (int j = 0; j < 3; ++j) o[j] = sB2[c * 3 + j];
    const float* zp = &zrows[n2 * RP];
#pragma unroll
    for (int k = 0; k < 16; ++k) {
      float zv = zp[k];
#pragma unroll
      for (int j = 0; j < 3; ++j) o[j] = fmaf(zv, sW2[k * 9 + c * 3 + j], o[j]);
    }
#pragma unroll
    for (int j = 0; j < 3; ++j) ost[n2 * 9 + c * 3 + j] = o[j];
  }
  __syncthreads();
  float* ob = out + (size_t)nbase * 9;
  for (int k = t; k < NPB * 9; k += 256) ob[k] = ost[k];
}

// ---------------- launch ----------------

extern "C" void kernel_launch(void* const* d_in, const int* in_sizes, int n_in,
                              void* d_out, int out_size, void* d_ws, size_t ws_size,
                              hipStream_t stream) {
  const float* x   = (const float*)d_in[0];
  const int*   ei  = (const int*)d_in[1];
  const float* W1  = (const float*)d_in[2];
  const float* b1  = (const float*)d_in[3];
  const float* W2  = (const float*)d_in[4];
  const float* b2  = (const float*)d_in[5];
  const float* W3  = (const float*)d_in[6];
  const float* b3  = (const float*)d_in[7];
  const float* W4  = (const float*)d_in[8];
  const float* b4  = (const float*)d_in[9];
  const float* W5  = (const float*)d_in[10];
  const float* b5  = (const float*)d_in[11];
  const float* fW1 = (const float*)d_in[12];
  const float* fb1 = (const float*)d_in[13];
  const float* fW2 = (const float*)d_in[14];
  const float* fb2 = (const float*)d_in[15];
  float* out = (float*)d_out;

  char* ws = (char*)d_ws;
  size_t off = 0;
  auto alloc = [&](size_t bytes) -> char* {
    char* p = ws + off;
    off += (bytes + 255) & ~(size_t)255;
    return p;
  };
  int*   counts  = (int*)  alloc((size_t)NBLK * NBKT * 4);
  int*   basesT  = (int*)  alloc((size_t)NBKT * NBLK * 4);
  int*   btot    = (int*)  alloc((size_t)NBKT * 4);
  int*   pbase   = (int*)  alloc((size_t)(NBKT + 1) * 4);
  unsigned int* pairs = (unsigned int*)alloc((size_t)NEDGE * 4);
  int*   rs_     = (int*)  alloc((size_t)NN * 4);
  int*   re_     = (int*)  alloc((size_t)NN * 4);
  float* dinv    = (float*)alloc((size_t)NN * 4);
  int*   csr     = (int*)  alloc((size_t)ETOT * 4);
  float* P16a    = (float*)alloc((size_t)NN * 16 * 4);
  float* P16b    = (float*)alloc((size_t)NN * 16 * 4);
  float* P32a    = (float*)alloc((size_t)NN * 32 * 4);
  float* P32b    = (float*)alloc((size_t)NN * 32 * 4);

  k_count<<<NBLK, 256, 0, stream>>>(ei, counts);
  k_scan <<<NBKT, 256, 0, stream>>>(counts, basesT, btot);
  k_pscan<<<1, 1024, 0, stream>>>(btot, pbase);
  k_scat <<<NBLK, 256, 0, stream>>>(ei, basesT, pbase, pairs);
  k_build<<<NBKT, 256, 0, stream>>>(pairs, pbase, rs_, re_, dinv, csr);

  // K1: g0 = dinv⊙(x@W1)
  k_gemm1<<<NN / 256, 256, 0, stream>>>(x, W1, dinv, P16a);
  // K2: g1 = dinv⊙relu(dinv·Σg0 + b1)
  k_agg_ep16<<<NN / 64, 256, 0, stream>>>(P16a, rs_, re_, csr, dinv, b1, P16b);
  // K3: g2 = dinv⊙relu((dinv·Σg1)@W2 + b2)
  k_agg_g2<<<NN / 64, 256, 0, stream>>>(P16b, rs_, re_, csr, dinv, W2, b2, P32a);
  // K4: g4 = dinv⊙(relu((dinv·Σg2)@W3+b3)@W4)
  k_agg_g34<<<NN / 32, 256, 0, stream>>>(P32a, rs_, re_, csr, dinv, W3, b3, W4, P32b);
  // K5: g5 = dinv⊙(relu(dinv·Σg4 + b4)@W5)
  k_agg_g5<<<NN / 32, 256, 0, stream>>>(P32b, rs_, re_, csr, dinv, b4, W5, P16a);
  // K6: head MLP on h5 = relu(dinv·Σg5 + b5)
  k_agg_mlp<<<NN / 64, 256, 0, stream>>>(P16a, rs_, re_, csr, dinv, b5,
                                         fW1, fb1, fW2, fb2, out);
}